// Round 3
// baseline (424.666 us; speedup 1.0000x reference)
//
#include <hip/hip_runtime.h>

// Orthonormal real spherical harmonics l=0..3, e3nn ordering.
#define C00  0.28209479177387814f   // 0.5*sqrt(1/pi)
#define C1   0.4886025119029199f    // sqrt(3/(4pi))
#define C2M2 1.0925484305920792f    // 0.5*sqrt(15/pi)
#define C20  0.31539156525252005f   // 0.25*sqrt(5/pi)
#define C22  0.5462742152960396f    // 0.25*sqrt(15/pi)
#define C3M3 0.5900435899266435f    // 0.25*sqrt(35/(2pi))
#define C3M2 2.890611442640554f     // 0.5*sqrt(105/pi)
#define C3M1 0.4570457994644658f    // 0.25*sqrt(21/(2pi))
#define C30  0.3731763325901154f    // 0.25*sqrt(7/pi)
#define C32  1.445305721320277f     // 0.25*sqrt(105/pi)

// Native clang vector type — __builtin_nontemporal_store requires a
// vector-of-float pointer, not HIP's float4 class type.
typedef float vfloat4 __attribute__((ext_vector_type(4)));

// One edge = 16 floats = exactly one 64 B cache line. Each thread owns its
// line outright: 4 back-to-back nt dwordx4 stores fully cover it — no
// partial-line write hazard, so the LDS output-transpose is unnecessary.
// Input is staged through a tiny LDS buffer so the global reads are fully
// coalesced float4 (the packed-float3 layout can't coalesce per-thread).
__global__ __launch_bounds__(256) void sh_l3_kernel(
    const float* __restrict__ v, float* __restrict__ out) {
    __shared__ float vin[768];                 // 256 edges * 3 floats = 3 KB

    const int t = threadIdx.x;
    const unsigned gbase = blockIdx.x * 256u;  // first edge of this block
    const unsigned edge = gbase + t;

    // ---- Stage 3 KB of input: 192 coalesced float4 loads ----
    if (t < 192) {
        const vfloat4* vg = reinterpret_cast<const vfloat4*>(v)
                          + 192ull * blockIdx.x;
        reinterpret_cast<vfloat4*>(vin)[t] = vg[t];
    }
    __syncthreads();

    // LDS read at stride 3: gcd(3,32)=1 → 2 lanes/bank over 64 lanes (free).
    float x = vin[3 * t + 0];
    float y = vin[3 * t + 1];
    float z = vin[3 * t + 2];

    float rinv = rsqrtf(x * x + y * y + z * z);
    x *= rinv; y *= rinv; z *= rinv;

    float x2 = x * x, y2 = y * y, z2 = z * z;

    vfloat4 o0, o1, o2, o3;
    o0.x = C00;                         // l=0
    o0.y = C1 * y;                      // l=1 m=-1
    o0.z = C1 * z;                      // l=1 m=0
    o0.w = C1 * x;                      // l=1 m=1
    o1.x = C2M2 * x * y;                // l=2 m=-2
    o1.y = C2M2 * y * z;                // l=2 m=-1
    o1.z = C20 * (3.0f * z2 - 1.0f);    // l=2 m=0
    o1.w = C2M2 * x * z;                // l=2 m=1
    o2.x = C22 * (x2 - y2);             // l=2 m=2
    o2.y = C3M3 * y * (3.0f * x2 - y2);     // l=3 m=-3
    o2.z = C3M2 * x * y * z;                // l=3 m=-2
    o2.w = C3M1 * y * (5.0f * z2 - 1.0f);   // l=3 m=-1
    o3.x = C30 * z * (5.0f * z2 - 3.0f);    // l=3 m=0
    o3.y = C3M1 * x * (5.0f * z2 - 1.0f);   // l=3 m=1
    o3.z = C32 * z * (x2 - y2);             // l=3 m=2
    o3.w = C3M3 * x * (x2 - 3.0f * y2);     // l=3 m=3

    // ---- Direct streaming stores: this thread's own 64 B line ----
    vfloat4* o = reinterpret_cast<vfloat4*>(out) + 4ull * edge;
    __builtin_nontemporal_store(o0, o + 0);
    __builtin_nontemporal_store(o1, o + 1);
    __builtin_nontemporal_store(o2, o + 2);
    __builtin_nontemporal_store(o3, o + 3);
}

extern "C" void kernel_launch(void* const* d_in, const int* in_sizes, int n_in,
                              void* d_out, int out_size, void* d_ws, size_t ws_size,
                              hipStream_t stream) {
    const float* v = (const float*)d_in[0];
    float* out = (float*)d_out;
    int n = in_sizes[0] / 3;                 // 4,000,000
    int grid = n / 256;                      // 15625 exactly (no tail)
    sh_l3_kernel<<<grid, 256, 0, stream>>>(v, out);
}

// Round 4
// 283.611 us; speedup vs baseline: 1.4974x; 1.4974x over previous
//
#include <hip/hip_runtime.h>

// Orthonormal real spherical harmonics l=0..3, e3nn ordering.
#define C00  0.28209479177387814f   // 0.5*sqrt(1/pi)
#define C1   0.4886025119029199f    // sqrt(3/(4pi))
#define C2M2 1.0925484305920792f    // 0.5*sqrt(15/pi)
#define C20  0.31539156525252005f   // 0.25*sqrt(5/pi)
#define C22  0.5462742152960396f    // 0.25*sqrt(15/pi)
#define C3M3 0.5900435899266435f    // 0.25*sqrt(35/(2pi))
#define C3M2 2.890611442640554f     // 0.5*sqrt(105/pi)
#define C3M1 0.4570457994644658f    // 0.25*sqrt(21/(2pi))
#define C30  0.3731763325901154f    // 0.25*sqrt(7/pi)
#define C32  1.445305721320277f     // 0.25*sqrt(105/pi)

// Native clang vector type — __builtin_nontemporal_store requires a
// vector-of-float pointer, not HIP's float4 class type.
typedef float vfloat4 __attribute__((ext_vector_type(4)));

// LDS pitch 260 (= 256 + 4 pad floats): both transpose phases are
// 2-way-or-better on the 32 banks (2-way is free on CDNA4 — m136).
#define PITCH 260

// Structure (evidence-driven, R2+R3):
//  * Store side MUST be lane-contiguous (R3 counter-proof: per-lane 64B-line
//    stores caused 540MB HBM writes = 2.1x amplification with nt stores).
//    LDS transpose -> lane-contiguous float4 nt stores: each wave store
//    instr fully covers 16 cache lines. WRITE_SIZE == 256MB.
//  * Input staged via coalesced float4 loads into 3KB LDS (R3: works, and
//    input is L3-resident anyway, FETCH ~23MB) instead of 3 strided scalar
//    global loads per thread.
__global__ __launch_bounds__(256) void sh_l3_kernel(
    const float* __restrict__ v, float* __restrict__ out) {
    __shared__ float vin[768];        // 256 edges * 3 floats = 3 KB
    __shared__ float sh[16][PITCH];   // 16 components x 256 edges (padded)

    const int t = threadIdx.x;
    const unsigned gbase = blockIdx.x * 256u;  // first edge of this block

    // ---- Stage 3 KB of input: 192 coalesced float4 loads ----
    if (t < 192) {
        const vfloat4* vg = reinterpret_cast<const vfloat4*>(v)
                          + 192ull * blockIdx.x;
        reinterpret_cast<vfloat4*>(vin)[t] = vg[t];
    }
    __syncthreads();

    // LDS read at stride 3: gcd(3,32)=1 -> 2 lanes/bank over 64 lanes (free).
    float x = vin[3 * t + 0];
    float y = vin[3 * t + 1];
    float z = vin[3 * t + 2];

    float rinv = rsqrtf(x * x + y * y + z * z);
    x *= rinv; y *= rinv; z *= rinv;

    float x2 = x * x, y2 = y * y, z2 = z * z;

    sh[0][t]  = C00;                        // l=0
    sh[1][t]  = C1 * y;                     // l=1 m=-1
    sh[2][t]  = C1 * z;                     // l=1 m=0
    sh[3][t]  = C1 * x;                     // l=1 m=1
    sh[4][t]  = C2M2 * x * y;               // l=2 m=-2
    sh[5][t]  = C2M2 * y * z;               // l=2 m=-1
    sh[6][t]  = C20 * (3.0f * z2 - 1.0f);   // l=2 m=0
    sh[7][t]  = C2M2 * x * z;               // l=2 m=1
    sh[8][t]  = C22 * (x2 - y2);            // l=2 m=2
    sh[9][t]  = C3M3 * y * (3.0f * x2 - y2);    // l=3 m=-3
    sh[10][t] = C3M2 * x * y * z;               // l=3 m=-2
    sh[11][t] = C3M1 * y * (5.0f * z2 - 1.0f);  // l=3 m=-1
    sh[12][t] = C30 * z * (5.0f * z2 - 3.0f);   // l=3 m=0
    sh[13][t] = C3M1 * x * (5.0f * z2 - 1.0f);  // l=3 m=1
    sh[14][t] = C32 * z * (x2 - y2);            // l=3 m=2
    sh[15][t] = C3M3 * x * (x2 - 3.0f * y2);    // l=3 m=3

    __syncthreads();

    // ---- Lane-contiguous float4 nt stores (1 KB per wave-instr) ----
    // Block writes 256 edges * 16 floats = 4096 floats = 1024 float4s.
    vfloat4* out4 = reinterpret_cast<vfloat4*>(out) + 4ull * gbase;
    #pragma unroll
    for (int k = 0; k < 4; ++k) {
        unsigned idx4 = k * 256u + t;       // float4 index within block tile
        unsigned e  = idx4 >> 2;            // edge within tile
        unsigned c  = (idx4 & 3u) * 4u;     // first component of this float4
        vfloat4 w;
        w.x = sh[c + 0][e];
        w.y = sh[c + 1][e];
        w.z = sh[c + 2][e];
        w.w = sh[c + 3][e];
        __builtin_nontemporal_store(w, &out4[idx4]);
    }
}

extern "C" void kernel_launch(void* const* d_in, const int* in_sizes, int n_in,
                              void* d_out, int out_size, void* d_ws, size_t ws_size,
                              hipStream_t stream) {
    const float* v = (const float*)d_in[0];
    float* out = (float*)d_out;
    int n = in_sizes[0] / 3;                 // 4,000,000
    int grid = n / 256;                      // 15625 exactly (no tail)
    sh_l3_kernel<<<grid, 256, 0, stream>>>(v, out);
}

// Round 5
// 282.828 us; speedup vs baseline: 1.5015x; 1.0028x over previous
//
#include <hip/hip_runtime.h>

// Orthonormal real spherical harmonics l=0..3, e3nn ordering.
#define C00  0.28209479177387814f   // 0.5*sqrt(1/pi)
#define C1   0.4886025119029199f    // sqrt(3/(4pi))
#define C2M2 1.0925484305920792f    // 0.5*sqrt(15/pi)
#define C20  0.31539156525252005f   // 0.25*sqrt(5/pi)
#define C22  0.5462742152960396f    // 0.25*sqrt(15/pi)
#define C3M3 0.5900435899266435f    // 0.25*sqrt(35/(2pi))
#define C3M2 2.890611442640554f     // 0.5*sqrt(105/pi)
#define C3M1 0.4570457994644658f    // 0.25*sqrt(21/(2pi))
#define C30  0.3731763325901154f    // 0.25*sqrt(7/pi)
#define C32  1.445305721320277f     // 0.25*sqrt(105/pi)

// Native clang vector type — __builtin_nontemporal_store requires a
// vector-of-float pointer, not HIP's float4 class type.
typedef float vfloat4 __attribute__((ext_vector_type(4)));

#define NBLOCKS 2048   // 8 blocks/CU * 256 CUs: fully resident, persistent

// Persistent-block pipelined structure (R4 post-mortem):
//  * R3 proved: stores MUST be lane-contiguous (per-lane 64B lines -> 2.1x
//    write amplification with nt). Kept: wave store = 1KB contiguous.
//  * R0/R2/R4 all ~identical => kernel limited by store-stream duty cycle
//    (per-block load-latency head + drain tail), not per-instr efficiency.
//    Fix: 2048 resident blocks grid-stride over tiles; double-buffered input
//    LDS; next tile's loads issued BEFORE current tile's compute+store.
//  * Store slot k*256+t has component-group c = t&3 (256 % 4 == 0), so each
//    thread computes all 16 components (redundant x4 — VALU is ~3% busy) and
//    selects its own float4: no 16.6KB transpose LDS, one barrier/iter.
__global__ __launch_bounds__(256) void sh_l3_kernel(
    const float* __restrict__ v, float* __restrict__ out, int ntiles) {
    __shared__ float vin[2][768];            // 2 x (256 edges * 3 floats)

    const int t = threadIdx.x;
    const unsigned c = t & 3u;               // my component group (fixed)
    const unsigned esub = t >> 2;            // my edge sub-index 0..63

    const vfloat4* v4 = reinterpret_cast<const vfloat4*>(v);
    vfloat4* out4 = reinterpret_cast<vfloat4*>(out);

    // Prologue: stage first tile (192 coalesced float4 loads).
    unsigned tile = blockIdx.x;
    if (tile < (unsigned)ntiles && t < 192)
        reinterpret_cast<vfloat4*>(vin[0])[t] = v4[192u * tile + t];
    __syncthreads();

    for (unsigned i = 0; tile < (unsigned)ntiles; tile += NBLOCKS, ++i) {
        const unsigned cur = i & 1u;

        // Issue next tile's loads first: HBM latency hides under this
        // tile's compute + store burst. Writes buf^1 (read two iters apart,
        // protected by the end-of-iteration barrier).
        const unsigned nxt = tile + NBLOCKS;
        if (nxt < (unsigned)ntiles && t < 192)
            reinterpret_cast<vfloat4*>(vin[cur ^ 1u])[t] = v4[192u * nxt + t];

        const unsigned long long obase = 1024ull * tile;
        #pragma unroll
        for (int k = 0; k < 4; ++k) {
            const unsigned e = (unsigned)k * 64u + esub;   // edge in tile
            // 4-lane-broadcast LDS reads (same addr per quad): conflict-free.
            float x = vin[cur][3u * e + 0u];
            float y = vin[cur][3u * e + 1u];
            float z = vin[cur][3u * e + 2u];

            float rinv = rsqrtf(x * x + y * y + z * z);
            x *= rinv; y *= rinv; z *= rinv;
            float x2 = x * x, y2 = y * y, z2 = z * z;

            vfloat4 o0, o1, o2, o3;
            o0.x = C00;                         // l=0
            o0.y = C1 * y;                      // l=1 m=-1
            o0.z = C1 * z;                      // l=1 m=0
            o0.w = C1 * x;                      // l=1 m=1
            o1.x = C2M2 * x * y;                // l=2 m=-2
            o1.y = C2M2 * y * z;                // l=2 m=-1
            o1.z = C20 * (3.0f * z2 - 1.0f);    // l=2 m=0
            o1.w = C2M2 * x * z;                // l=2 m=1
            o2.x = C22 * (x2 - y2);             // l=2 m=2
            o2.y = C3M3 * y * (3.0f * x2 - y2);     // l=3 m=-3
            o2.z = C3M2 * x * y * z;                // l=3 m=-2
            o2.w = C3M1 * y * (5.0f * z2 - 1.0f);   // l=3 m=-1
            o3.x = C30 * z * (5.0f * z2 - 3.0f);    // l=3 m=0
            o3.y = C3M1 * x * (5.0f * z2 - 1.0f);   // l=3 m=1
            o3.z = C32 * z * (x2 - y2);             // l=3 m=2
            o3.w = C3M3 * x * (x2 - 3.0f * y2);     // l=3 m=3

            vfloat4 w = o0;
            w = (c == 1u) ? o1 : w;
            w = (c == 2u) ? o2 : w;
            w = (c == 3u) ? o3 : w;

            // Lane-contiguous: wave covers 1KB = 16 full cache lines.
            __builtin_nontemporal_store(w, &out4[obase + (unsigned)k * 256u + (unsigned)t]);
        }
        __syncthreads();   // protects vin[cur] reads vs next iter's writes
    }
}

extern "C" void kernel_launch(void* const* d_in, const int* in_sizes, int n_in,
                              void* d_out, int out_size, void* d_ws, size_t ws_size,
                              hipStream_t stream) {
    const float* v = (const float*)d_in[0];
    float* out = (float*)d_out;
    int n = in_sizes[0] / 3;                 // 4,000,000
    int ntiles = n / 256;                    // 15625 exactly (no tail)
    int grid = ntiles < NBLOCKS ? ntiles : NBLOCKS;
    sh_l3_kernel<<<grid, 256, 0, stream>>>(v, out, ntiles);
}

// Round 6
// 281.053 us; speedup vs baseline: 1.5110x; 1.0063x over previous
//
#include <hip/hip_runtime.h>

// Orthonormal real spherical harmonics l=0..3, e3nn ordering.
#define C00  0.28209479177387814f   // 0.5*sqrt(1/pi)
#define C1   0.4886025119029199f    // sqrt(3/(4pi))
#define C2M2 1.0925484305920792f    // 0.5*sqrt(15/pi)
#define C20  0.31539156525252005f   // 0.25*sqrt(5/pi)
#define C22  0.5462742152960396f    // 0.25*sqrt(15/pi)
#define C3M3 0.5900435899266435f    // 0.25*sqrt(35/(2pi))
#define C3M2 2.890611442640554f     // 0.5*sqrt(105/pi)
#define C3M1 0.4570457994644658f    // 0.25*sqrt(21/(2pi))
#define C30  0.3731763325901154f    // 0.25*sqrt(7/pi)
#define C32  1.445305721320277f     // 0.25*sqrt(105/pi)

typedef float vfloat4 __attribute__((ext_vector_type(4)));

#define NBLOCKS 2048   // 8 blocks/CU * 256 CUs, persistent
#define MAXIT   8      // ceil(15625 / 2048)

// Barrier-free, LDS-free register pipeline (R5 post-mortem):
//  * R3 proved stores must be lane-contiguous (else 2.1x write amplification).
//  * R0/R2/R4/R5 (transpose-LDS / staged / persistent-dbuf) all tie at
//    283-288us => remaining gap is store-stream asynchrony, not per-instr.
//  * This version has NO __syncthreads and NO LDS: the output transpose is
//    intra-wave. Lane l of wave w owns edge eo=(l>>4)*64+16w+(l&15); store
//    slot k*256+t needs edge k*64+16w+(l>>2), owned by lane (k<<4)|(l>>2)
//    of the SAME wave -> 3 __shfl per k. Comp group = t&3. Each lane
//    front-loads all its tiles' x,y,z (<=24 outstanding scalar loads,
//    L3-resident input) so reads never interrupt the store stream.
__global__ __launch_bounds__(256) void sh_l3_kernel(
    const float* __restrict__ v, float* __restrict__ out, int ntiles) {
    const int t = threadIdx.x;
    const int w = t >> 6;          // wave 0..3
    const int l = t & 63;          // lane 0..63
    const int eo = ((l >> 4) << 6) + (w << 4) + (l & 15);  // owned edge in tile
    const int c = l & 3;           // my component group (== t&3)

    float xs[MAXIT], ys[MAXIT], zs[MAXIT];

    // ---- Front-load all owned inputs (static indices: stays in VGPRs) ----
    #pragma unroll
    for (int i = 0; i < MAXIT; ++i) {
        const unsigned tile = blockIdx.x + (unsigned)i * NBLOCKS;
        if (tile < (unsigned)ntiles) {
            const float* p = v + 768ull * tile + 3u * (unsigned)eo;
            xs[i] = p[0]; ys[i] = p[1]; zs[i] = p[2];
        }
    }

    vfloat4* out4 = reinterpret_cast<vfloat4*>(out);

    #pragma unroll
    for (int i = 0; i < MAXIT; ++i) {
        const unsigned tile = blockIdx.x + (unsigned)i * NBLOCKS;
        if (tile >= (unsigned)ntiles) break;   // block-uniform: no divergence

        // Normalize the owned edge once (1 rsqrt/tile), then shuffle.
        float x = xs[i], y = ys[i], z = zs[i];
        float rinv = rsqrtf(x * x + y * y + z * z);
        x *= rinv; y *= rinv; z *= rinv;

        const unsigned obase = 1024u * tile;
        #pragma unroll
        for (int k = 0; k < 4; ++k) {
            const int src = (k << 4) | (l >> 2);   // same-wave owner lane
            float sx = __shfl(x, src);
            float sy = __shfl(y, src);
            float sz = __shfl(z, src);
            float x2 = sx * sx, y2 = sy * sy, z2 = sz * sz;

            vfloat4 o0, o1, o2, o3;
            o0.x = C00;                          // l=0
            o0.y = C1 * sy;                      // l=1 m=-1
            o0.z = C1 * sz;                      // l=1 m=0
            o0.w = C1 * sx;                      // l=1 m=1
            o1.x = C2M2 * sx * sy;               // l=2 m=-2
            o1.y = C2M2 * sy * sz;               // l=2 m=-1
            o1.z = C20 * (3.0f * z2 - 1.0f);     // l=2 m=0
            o1.w = C2M2 * sx * sz;               // l=2 m=1
            o2.x = C22 * (x2 - y2);              // l=2 m=2
            o2.y = C3M3 * sy * (3.0f * x2 - y2);     // l=3 m=-3
            o2.z = C3M2 * sx * sy * sz;              // l=3 m=-2
            o2.w = C3M1 * sy * (5.0f * z2 - 1.0f);   // l=3 m=-1
            o3.x = C30 * sz * (5.0f * z2 - 3.0f);    // l=3 m=0
            o3.y = C3M1 * sx * (5.0f * z2 - 1.0f);   // l=3 m=1
            o3.z = C32 * sz * (x2 - y2);             // l=3 m=2
            o3.w = C3M3 * sx * (x2 - 3.0f * y2);     // l=3 m=3

            vfloat4 wv = o0;
            wv = (c == 1) ? o1 : wv;
            wv = (c == 2) ? o2 : wv;
            wv = (c == 3) ? o3 : wv;

            // Lane-contiguous: each wave store covers 1KB = 16 full lines.
            __builtin_nontemporal_store(
                wv, &out4[obase + (unsigned)(k << 8) + (unsigned)t]);
        }
    }
}

extern "C" void kernel_launch(void* const* d_in, const int* in_sizes, int n_in,
                              void* d_out, int out_size, void* d_ws, size_t ws_size,
                              hipStream_t stream) {
    const float* v = (const float*)d_in[0];
    float* out = (float*)d_out;
    int n = in_sizes[0] / 3;                 // 4,000,000
    int ntiles = n / 256;                    // 15625 exactly (no tail)
    int grid = ntiles < NBLOCKS ? ntiles : NBLOCKS;
    sh_l3_kernel<<<grid, 256, 0, stream>>>(v, out, ntiles);
}